// Round 1
// baseline (439.753 us; speedup 1.0000x reference)
//
#include <hip/hip_runtime.h>
#include <hip/hip_bf16.h>
#include <hip/hip_fp16.h>

#define EMB 64
#define SCAN_CHUNK 1024   // 256 threads x 4 elems per scan block

// ---- dtype-flexible loads ---------------------------------------------------
__device__ __forceinline__ float ld_elem(const void* p, long long i, int bf) {
    if (bf) return (float)((const __hip_bfloat16*)p)[i];
    return ((const float*)p)[i];
}
__device__ __forceinline__ float ld_x0(const void* uw, const void* iw,
                                       int n_user_elems, long long elem, int bf) {
    if (elem < (long long)n_user_elems) return ld_elem(uw, elem, bf);
    return ld_elem(iw, elem - n_user_elems, bf);
}

// ---- histogram + fused dtype probe -----------------------------------------
__global__ void hist_rows(const int* __restrict__ rows, int* __restrict__ counts, int nnz,
                          const unsigned short* __restrict__ v16, int* __restrict__ flag) {
    int tid = blockIdx.x * blockDim.x + threadIdx.x;
    int stride = gridDim.x * blockDim.x;
    for (int e = tid; e < nnz; e += stride) atomicAdd(&counts[rows[e]], 1);
    if (tid == 0) {
        int hits = 0;
        for (int i = 0; i < 256; ++i) {
            unsigned int hb = v16[i] >> 8;
            unsigned int ex = hb & 0x7F;
            if (hb < 0x80 && ex >= 0x30 && ex < 0x40) hits++;
        }
        *flag = (hits >= 200) ? 1 : 0;   // 1 = bf16, 0 = fp32
    }
}

// ---- scan phase 1: per-block exclusive scan + block sums -------------------
__global__ void scan_blocks(const int* __restrict__ in, int* __restrict__ excl,
                            int* __restrict__ blocksums, int n) {
    __shared__ int lds[256];
    int base = blockIdx.x * SCAN_CHUNK;
    int t = threadIdx.x;
    int c[4]; int s = 0;
    for (int k = 0; k < 4; ++k) {
        int i = base + t * 4 + k;
        c[k] = (i < n) ? in[i] : 0;
        s += c[k];
    }
    lds[t] = s;
    __syncthreads();
    for (int off = 1; off < 256; off <<= 1) {
        int v = lds[t];
        int add = (t >= off) ? lds[t - off] : 0;
        __syncthreads();
        lds[t] = v + add;
        __syncthreads();
    }
    int run = (t > 0) ? lds[t - 1] : 0;
    if (t == 255) blocksums[blockIdx.x] = lds[255];
    for (int k = 0; k < 4; ++k) {
        int i = base + t * 4 + k;
        if (i < n) excl[i] = run;
        run += c[k];
    }
}

// ---- scan phase 2 (fused): every block re-scans blocksums in LDS, fixes up --
__global__ void scan_fixup(int* __restrict__ excl, const int* __restrict__ bsums,
                           int* __restrict__ offs, int n, int nrows, int nb) {
    __shared__ int lds[256];
    int t = threadIdx.x;
    lds[t] = (t < nb) ? bsums[t] : 0;
    __syncthreads();
    for (int off = 1; off < 256; off <<= 1) {
        int v = lds[t];
        int add = (t >= off) ? lds[t - off] : 0;
        __syncthreads();
        lds[t] = v + add;
        __syncthreads();
    }
    __syncthreads();
    int i = blockIdx.x * blockDim.x + threadIdx.x;
    if (i >= n) return;
    int b = i / SCAN_CHUNK;
    int v = excl[i] + (b > 0 ? lds[b - 1] : 0);
    excl[i] = v;                 // excl becomes row_ptr
    if (i < nrows) offs[i] = v;  // scatter cursors
}

// ---- scatter edges into row-sorted packed (val,col) records ----------------
__global__ void scatter_edges(const void* __restrict__ vals, const int* __restrict__ rows,
                              const int* __restrict__ cols, int* __restrict__ offs,
                              float2* __restrict__ edges, int nnz,
                              const int* __restrict__ flagp) {
    int e = blockIdx.x * blockDim.x + threadIdx.x;
    if (e >= nnz) return;
    int bf = *flagp;
    float v = ld_elem(vals, e, bf);
    int r = rows[e];
    int pos = atomicAdd(&offs[r], 1);
    float2 rec; rec.x = v; rec.y = __int_as_float(cols[e]);
    edges[pos] = rec;
}

// ---- gather-only SpMM: one wave per row, lane = dim, 4-wide MLP ------------
// GMODE: 0 = gather x0 (inputs, dtype via flag), 1 = gather fp16 g
// OMODE: 1 = write g' = x0 + acc as fp16, 3 = final (x0+acc)*0.25 (dtype via flag)
template <int GMODE, int OMODE>
__global__ void spmm_csr(const int* __restrict__ row_ptr,
                         const float2* __restrict__ edges,
                         const void* __restrict__ uw, const void* __restrict__ iw,
                         int n_user_elems,
                         const __half* __restrict__ gin, void* __restrict__ gout,
                         int nrows, const int* __restrict__ flagp) {
    int wid  = (blockIdx.x * blockDim.x + threadIdx.x) >> 6;
    int lane = threadIdx.x & 63;
    if (wid >= nrows) return;
    int bf = *flagp;
    int beg = row_ptr[wid], end = row_ptr[wid + 1];
    float acc = 0.0f;

#define GATHER(E, XD) { \
        long long ce = (long long)__float_as_int((E).y) * EMB + lane; \
        if (GMODE == 0) XD = ld_x0(uw, iw, n_user_elems, ce, bf); \
        else            XD = __half2float(gin[ce]); }

    int j = beg;
    for (; j + 4 <= end; j += 4) {
        float2 e0 = edges[j], e1 = edges[j + 1], e2 = edges[j + 2], e3 = edges[j + 3];
        float xa, xb, xc, xd;
        GATHER(e0, xa); GATHER(e1, xb); GATHER(e2, xc); GATHER(e3, xd);
        acc += e0.x * xa; acc += e1.x * xb; acc += e2.x * xc; acc += e3.x * xd;
    }
    if (j + 2 <= end) {
        float2 e0 = edges[j], e1 = edges[j + 1];
        float xa, xb;
        GATHER(e0, xa); GATHER(e1, xb);
        acc += e0.x * xa; acc += e1.x * xb;
        j += 2;
    }
    if (j < end) {
        float2 e0 = edges[j];
        float xa; GATHER(e0, xa);
        acc += e0.x * xa;
    }
#undef GATHER

    long long re = (long long)wid * EMB + lane;
    float x0v = ld_x0(uw, iw, n_user_elems, re, bf);
    if (OMODE == 1) {
        ((__half*)gout)[re] = __float2half(x0v + acc);
    } else {
        float o = (x0v + acc) * 0.25f;
        if (bf) ((__hip_bfloat16*)gout)[re] = (__hip_bfloat16)o;
        else    ((float*)gout)[re] = o;
    }
}

extern "C" void kernel_launch(void* const* d_in, const int* in_sizes, int n_in,
                              void* d_out, int out_size, void* d_ws, size_t ws_size,
                              hipStream_t stream) {
    const void* uw   = d_in[0];
    const void* iw   = d_in[1];
    const void* vals = d_in[2];
    const int*  rows = (const int*)d_in[3];
    const int*  cols = (const int*)d_in[4];

    const int n_user = in_sizes[0];                // 6.4M elems
    const int total  = in_sizes[0] + in_sizes[1];  // 12.8M elems
    const int nnz    = in_sizes[2];                // 1M edges
    const int nrows  = total / EMB;                // 200K

    // ---- workspace layout (256B-aligned) ----
    char* p = (char*)d_ws;
    auto alloc = [&](size_t bytes) { char* q = p; p += (bytes + 255) & ~(size_t)255; return q; };
    int*    flag    = (int*)   alloc(sizeof(int));
    int*    row_ptr = (int*)   alloc((size_t)(nrows + 1) * sizeof(int));
    int*    counts  = (int*)   alloc((size_t)(nrows + 1) * sizeof(int));
    int*    offs    = (int*)   alloc((size_t)nrows * sizeof(int));
    int*    bsums   = (int*)   alloc(1024 * sizeof(int));
    float2* edges   = (float2*)alloc((size_t)nnz * sizeof(float2));
    size_t used = (size_t)(p - (char*)d_ws);
    size_t avail = (ws_size > used) ? ws_size - used : 0;

    const size_t g_f16 = (size_t)total * sizeof(__half);  // 25.6 MB
    __half *g2, *g3;
    if (avail >= 2 * g_f16 + 512) { g2 = (__half*)alloc(g_f16); g3 = (__half*)alloc(g_f16); }
    else { g2 = (__half*)d_out; g3 = (__half*)alloc(g_f16); }  // d_out dead-staged (same 2B/elem), overwritten at end

    // ---- CSR build (every call; capture-safe) ----
    hipMemsetAsync(counts, 0, (size_t)(nrows + 1) * sizeof(int), stream);
    const int hb = (nnz / 4 + 255) / 256;
    hist_rows<<<hb, 256, 0, stream>>>(rows, counts, nnz, (const unsigned short*)vals, flag);
    const int n_scan = nrows + 1;
    const int nb = (n_scan + SCAN_CHUNK - 1) / SCAN_CHUNK;   // 196 <= 256
    scan_blocks<<<nb, 256, 0, stream>>>(counts, row_ptr, bsums, n_scan);
    scan_fixup<<<(n_scan + 255) / 256, 256, 0, stream>>>(row_ptr, bsums, offs, n_scan, nrows, nb);
    const int eb = (nnz + 255) / 256;
    scatter_edges<<<eb, 256, 0, stream>>>(vals, rows, cols, offs, edges, nnz, flag);

    // ---- 3 gather-only SpMM layers (Horner), fp16 inter-layer staging ----
    const int rb = (nrows * EMB + 255) / 256;   // one wave per row
    spmm_csr<0, 1><<<rb, 256, 0, stream>>>(row_ptr, edges, uw, iw, n_user,
                                           nullptr, g2, nrows, flag);
    spmm_csr<1, 1><<<rb, 256, 0, stream>>>(row_ptr, edges, uw, iw, n_user,
                                           g2, g3, nrows, flag);
    spmm_csr<1, 3><<<rb, 256, 0, stream>>>(row_ptr, edges, uw, iw, n_user,
                                           g3, d_out, nrows, flag);
}

// Round 2
// 329.379 us; speedup vs baseline: 1.3351x; 1.3351x over previous
//
#include <hip/hip_runtime.h>
#include <hip/hip_bf16.h>
#include <hip/hip_fp16.h>

#define EMB 64
#define SCAN_CHUNK 1024   // 256 threads x 4 elems per scan block

// ---- dtype-flexible loads ---------------------------------------------------
__device__ __forceinline__ float ld_elem(const void* p, long long i, int bf) {
    if (bf) return (float)((const __hip_bfloat16*)p)[i];
    return ((const float*)p)[i];
}

// ---- histogram + fused dtype probe -----------------------------------------
__global__ void hist_rows(const int* __restrict__ rows, int* __restrict__ counts, int nnz,
                          const unsigned short* __restrict__ v16, int* __restrict__ flag) {
    int tid = blockIdx.x * blockDim.x + threadIdx.x;
    int stride = gridDim.x * blockDim.x;
    for (int e = tid; e < nnz; e += stride) atomicAdd(&counts[rows[e]], 1);
    if (tid == 0) {
        int hits = 0;
        for (int i = 0; i < 256; ++i) {
            unsigned int hb = v16[i] >> 8;
            unsigned int ex = hb & 0x7F;
            if (hb < 0x80 && ex >= 0x30 && ex < 0x40) hits++;
        }
        *flag = (hits >= 200) ? 1 : 0;   // 1 = bf16, 0 = fp32
    }
}

// ---- scan phase 1: per-block exclusive scan + block sums -------------------
__global__ void scan_blocks(const int* __restrict__ in, int* __restrict__ excl,
                            int* __restrict__ blocksums, int n) {
    __shared__ int lds[256];
    int base = blockIdx.x * SCAN_CHUNK;
    int t = threadIdx.x;
    int c[4]; int s = 0;
    for (int k = 0; k < 4; ++k) {
        int i = base + t * 4 + k;
        c[k] = (i < n) ? in[i] : 0;
        s += c[k];
    }
    lds[t] = s;
    __syncthreads();
    for (int off = 1; off < 256; off <<= 1) {
        int v = lds[t];
        int add = (t >= off) ? lds[t - off] : 0;
        __syncthreads();
        lds[t] = v + add;
        __syncthreads();
    }
    int run = (t > 0) ? lds[t - 1] : 0;
    if (t == 255) blocksums[blockIdx.x] = lds[255];
    for (int k = 0; k < 4; ++k) {
        int i = base + t * 4 + k;
        if (i < n) excl[i] = run;
        run += c[k];
    }
}

// ---- scan phase 2 (fused): every block re-scans blocksums in LDS, fixes up --
__global__ void scan_fixup(int* __restrict__ excl, const int* __restrict__ bsums,
                           int* __restrict__ offs, int n, int nrows, int nb) {
    __shared__ int lds[256];
    int t = threadIdx.x;
    lds[t] = (t < nb) ? bsums[t] : 0;
    __syncthreads();
    for (int off = 1; off < 256; off <<= 1) {
        int v = lds[t];
        int add = (t >= off) ? lds[t - off] : 0;
        __syncthreads();
        lds[t] = v + add;
        __syncthreads();
    }
    __syncthreads();
    int i = blockIdx.x * blockDim.x + threadIdx.x;
    if (i >= n) return;
    int b = i / SCAN_CHUNK;
    int v = excl[i] + (b > 0 ? lds[b - 1] : 0);
    excl[i] = v;                 // excl becomes row_ptr
    if (i < nrows) offs[i] = v;  // scatter cursors
}

// ---- scatter edges into row-sorted packed (val,col) records ----------------
__global__ void scatter_edges(const void* __restrict__ vals, const int* __restrict__ rows,
                              const int* __restrict__ cols, int* __restrict__ offs,
                              float2* __restrict__ edges, int nnz,
                              const int* __restrict__ flagp) {
    int e = blockIdx.x * blockDim.x + threadIdx.x;
    if (e >= nnz) return;
    int bf = *flagp;
    float v = ld_elem(vals, e, bf);
    int r = rows[e];
    int pos = atomicAdd(&offs[r], 1);
    float2 rec; rec.x = v; rec.y = __int_as_float(cols[e]);
    edges[pos] = rec;
}

// ---- 4-elem gather helpers (elem index = 4 consecutive dims) ----------------
__device__ __forceinline__ float4 ld4_x0(const void* uw, const void* iw,
                                         int n_user_elems, long long e, int bf) {
    const void* base = uw;
    if (e >= (long long)n_user_elems) { base = iw; e -= n_user_elems; }
    if (bf) {
        uint2 r = *reinterpret_cast<const uint2*>((const unsigned short*)base + e);
        // bf16 -> f32 is exact via <<16
        return make_float4(__uint_as_float((r.x & 0xFFFFu) << 16),
                           __uint_as_float(r.x & 0xFFFF0000u),
                           __uint_as_float((r.y & 0xFFFFu) << 16),
                           __uint_as_float(r.y & 0xFFFF0000u));
    }
    return *reinterpret_cast<const float4*>((const float*)base + e);
}

__device__ __forceinline__ float4 ld4_f16(const __half* g, long long e) {
    uint2 r = *reinterpret_cast<const uint2*>(g + e);
    union { unsigned int u; __half2 h; } c0, c1;
    c0.u = r.x; c1.u = r.y;
    float2 f0 = __half22float2(c0.h), f1 = __half22float2(c1.h);
    return make_float4(f0.x, f0.y, f1.x, f1.y);
}

// ---- gather-only SpMM: 4 rows per wave, 16 lanes per row, lane = 4 dims ----
// GMODE: 0 = gather x0 (inputs, dtype via flag), 1 = gather fp16 g
// OMODE: 1 = write g' = x0 + acc as fp16, 3 = final (x0+acc)*0.25 (dtype via flag)
template <int GMODE, int OMODE>
__global__ void spmm_csr4(const int* __restrict__ row_ptr,
                          const float2* __restrict__ edges,
                          const void* __restrict__ uw, const void* __restrict__ iw,
                          int n_user_elems,
                          const __half* __restrict__ gin, void* __restrict__ gout,
                          int nrows, const int* __restrict__ flagp) {
    int tid  = blockIdx.x * blockDim.x + threadIdx.x;
    int wave = tid >> 6;
    int lane = threadIdx.x & 63;
    int g    = lane >> 4;          // row slot within wave (0..3)
    int l    = lane & 15;          // dim quad: covers dims [4l, 4l+3]
    int wid  = wave * 4 + g;
    if (wid >= nrows) return;
    int bf = *flagp;
    int beg = row_ptr[wid], end = row_ptr[wid + 1];
    float a0 = 0.f, a1 = 0.f, a2 = 0.f, a3 = 0.f;

#define GATHER(E, X) { \
        long long ce = (long long)__float_as_int((E).y) * EMB + l * 4; \
        if (GMODE == 0) X = ld4_x0(uw, iw, n_user_elems, ce, bf); \
        else            X = ld4_f16(gin, ce); }
#define ACC(E, X) { a0 += (E).x * (X).x; a1 += (E).x * (X).y; \
                    a2 += (E).x * (X).z; a3 += (E).x * (X).w; }

    int j = beg;
    for (; j + 4 <= end; j += 4) {
        float2 e0 = edges[j], e1 = edges[j + 1], e2 = edges[j + 2], e3 = edges[j + 3];
        float4 xa, xb, xc, xd;
        GATHER(e0, xa); GATHER(e1, xb); GATHER(e2, xc); GATHER(e3, xd);
        ACC(e0, xa); ACC(e1, xb); ACC(e2, xc); ACC(e3, xd);
    }
    if (j + 2 <= end) {
        float2 e0 = edges[j], e1 = edges[j + 1];
        float4 xa, xb;
        GATHER(e0, xa); GATHER(e1, xb);
        ACC(e0, xa); ACC(e1, xb);
        j += 2;
    }
    if (j < end) {
        float2 e0 = edges[j];
        float4 xa; GATHER(e0, xa);
        ACC(e0, xa);
    }
#undef GATHER
#undef ACC

    long long re = (long long)wid * EMB + l * 4;
    float4 x0v = ld4_x0(uw, iw, n_user_elems, re, bf);
    float o0 = x0v.x + a0, o1 = x0v.y + a1, o2 = x0v.z + a2, o3 = x0v.w + a3;

    if (OMODE == 1) {
        __half2 h01 = __floats2half2_rn(o0, o1);
        __half2 h23 = __floats2half2_rn(o2, o3);
        union { __half2 h; unsigned int u; } p0, p1;
        p0.h = h01; p1.h = h23;
        uint2 out; out.x = p0.u; out.y = p1.u;
        reinterpret_cast<uint2*>(gout)[re >> 2] = out;
    } else {
        o0 *= 0.25f; o1 *= 0.25f; o2 *= 0.25f; o3 *= 0.25f;
        if (bf) {
            __hip_bfloat16 b0 = (__hip_bfloat16)o0, b1 = (__hip_bfloat16)o1;
            __hip_bfloat16 b2 = (__hip_bfloat16)o2, b3 = (__hip_bfloat16)o3;
            unsigned short s0 = *reinterpret_cast<unsigned short*>(&b0);
            unsigned short s1 = *reinterpret_cast<unsigned short*>(&b1);
            unsigned short s2 = *reinterpret_cast<unsigned short*>(&b2);
            unsigned short s3 = *reinterpret_cast<unsigned short*>(&b3);
            uint2 out;
            out.x = (unsigned int)s0 | ((unsigned int)s1 << 16);
            out.y = (unsigned int)s2 | ((unsigned int)s3 << 16);
            reinterpret_cast<uint2*>(gout)[re >> 2] = out;
        } else {
            reinterpret_cast<float4*>(gout)[re >> 2] = make_float4(o0, o1, o2, o3);
        }
    }
}

extern "C" void kernel_launch(void* const* d_in, const int* in_sizes, int n_in,
                              void* d_out, int out_size, void* d_ws, size_t ws_size,
                              hipStream_t stream) {
    const void* uw   = d_in[0];
    const void* iw   = d_in[1];
    const void* vals = d_in[2];
    const int*  rows = (const int*)d_in[3];
    const int*  cols = (const int*)d_in[4];

    const int n_user = in_sizes[0];                // 6.4M elems
    const int total  = in_sizes[0] + in_sizes[1];  // 12.8M elems
    const int nnz    = in_sizes[2];                // 1M edges
    const int nrows  = total / EMB;                // 200K

    // ---- workspace layout (256B-aligned) ----
    char* p = (char*)d_ws;
    auto alloc = [&](size_t bytes) { char* q = p; p += (bytes + 255) & ~(size_t)255; return q; };
    int*    flag    = (int*)   alloc(sizeof(int));
    int*    row_ptr = (int*)   alloc((size_t)(nrows + 1) * sizeof(int));
    int*    counts  = (int*)   alloc((size_t)(nrows + 1) * sizeof(int));
    int*    offs    = (int*)   alloc((size_t)nrows * sizeof(int));
    int*    bsums   = (int*)   alloc(1024 * sizeof(int));
    float2* edges   = (float2*)alloc((size_t)nnz * sizeof(float2));
    size_t used = (size_t)(p - (char*)d_ws);
    size_t avail = (ws_size > used) ? ws_size - used : 0;

    const size_t g_f16 = (size_t)total * sizeof(__half);  // 25.6 MB
    __half *g2, *g3;
    if (avail >= 2 * g_f16 + 512) { g2 = (__half*)alloc(g_f16); g3 = (__half*)alloc(g_f16); }
    else { g2 = (__half*)d_out; g3 = (__half*)alloc(g_f16); }  // d_out dead-staged (same 2B/elem), overwritten at end

    // ---- CSR build (every call; capture-safe) ----
    hipMemsetAsync(counts, 0, (size_t)(nrows + 1) * sizeof(int), stream);
    const int hb = (nnz / 4 + 255) / 256;
    hist_rows<<<hb, 256, 0, stream>>>(rows, counts, nnz, (const unsigned short*)vals, flag);
    const int n_scan = nrows + 1;
    const int nb = (n_scan + SCAN_CHUNK - 1) / SCAN_CHUNK;   // 196 <= 256
    scan_blocks<<<nb, 256, 0, stream>>>(counts, row_ptr, bsums, n_scan);
    scan_fixup<<<(n_scan + 255) / 256, 256, 0, stream>>>(row_ptr, bsums, offs, n_scan, nrows, nb);
    const int eb = (nnz + 255) / 256;
    scatter_edges<<<eb, 256, 0, stream>>>(vals, rows, cols, offs, edges, nnz, flag);

    // ---- 3 gather-only SpMM layers (Horner), fp16 inter-layer staging ----
    // 4 rows per wave: nwaves = ceil(nrows/4)
    const int nwaves = (nrows + 3) / 4;
    const int rb = (nwaves * 64 + 255) / 256;
    spmm_csr4<0, 1><<<rb, 256, 0, stream>>>(row_ptr, edges, uw, iw, n_user,
                                            nullptr, g2, nrows, flag);
    spmm_csr4<1, 1><<<rb, 256, 0, stream>>>(row_ptr, edges, uw, iw, n_user,
                                            g2, g3, nrows, flag);
    spmm_csr4<1, 3><<<rb, 256, 0, stream>>>(row_ptr, edges, uw, iw, n_user,
                                            g3, d_out, nrows, flag);
}

// Round 3
// 300.023 us; speedup vs baseline: 1.4657x; 1.0978x over previous
//
#include <hip/hip_runtime.h>
#include <hip/hip_bf16.h>
#include <hip/hip_fp16.h>

#define EMB 64
#define SCAN_CHUNK 1024   // 256 threads x 4 elems per scan block
#define BSHIFT 11         // 2048 rows per bucket
#define BROWS (1 << BSHIFT)
#define NBMAX 128         // >= ceil(200000/2048)=98
#define TILE 4096         // edges per bucket_scatter tile

// ---- dtype-flexible loads ---------------------------------------------------
__device__ __forceinline__ float ld_elem(const void* p, long long i, int bf) {
    if (bf) return (float)((const __hip_bfloat16*)p)[i];
    return ((const float*)p)[i];
}

// ---- histogram + fused dtype probe -----------------------------------------
__global__ void hist_rows(const int* __restrict__ rows, int* __restrict__ counts, int nnz,
                          const unsigned short* __restrict__ v16, int* __restrict__ flag) {
    int tid = blockIdx.x * blockDim.x + threadIdx.x;
    int stride = gridDim.x * blockDim.x;
    for (int e = tid; e < nnz; e += stride) atomicAdd(&counts[rows[e]], 1);
    if (tid == 0) {
        int hits = 0;
        for (int i = 0; i < 256; ++i) {
            unsigned int hb = v16[i] >> 8;
            unsigned int ex = hb & 0x7F;
            if (hb < 0x80 && ex >= 0x30 && ex < 0x40) hits++;
        }
        *flag = (hits >= 200) ? 1 : 0;   // 1 = bf16, 0 = fp32
    }
}

// ---- scan phase 1: per-block exclusive scan + block sums -------------------
__global__ void scan_blocks(const int* __restrict__ in, int* __restrict__ excl,
                            int* __restrict__ blocksums, int n) {
    __shared__ int lds[256];
    int base = blockIdx.x * SCAN_CHUNK;
    int t = threadIdx.x;
    int c[4]; int s = 0;
    for (int k = 0; k < 4; ++k) {
        int i = base + t * 4 + k;
        c[k] = (i < n) ? in[i] : 0;
        s += c[k];
    }
    lds[t] = s;
    __syncthreads();
    for (int off = 1; off < 256; off <<= 1) {
        int v = lds[t];
        int add = (t >= off) ? lds[t - off] : 0;
        __syncthreads();
        lds[t] = v + add;
        __syncthreads();
    }
    int run = (t > 0) ? lds[t - 1] : 0;
    if (t == 255) blocksums[blockIdx.x] = lds[255];
    for (int k = 0; k < 4; ++k) {
        int i = base + t * 4 + k;
        if (i < n) excl[i] = run;
        run += c[k];
    }
}

// ---- scan phase 2 (fused): every block re-scans blocksums in LDS, fixes up --
// Also seeds per-bucket scatter cursors bcur[b] = row_ptr[b*BROWS].
__global__ void scan_fixup(int* __restrict__ excl, const int* __restrict__ bsums,
                           int* __restrict__ bcur, int n, int nrows, int nb) {
    __shared__ int lds[256];
    int t = threadIdx.x;
    lds[t] = (t < nb) ? bsums[t] : 0;
    __syncthreads();
    for (int off = 1; off < 256; off <<= 1) {
        int v = lds[t];
        int add = (t >= off) ? lds[t - off] : 0;
        __syncthreads();
        lds[t] = v + add;
        __syncthreads();
    }
    __syncthreads();
    int i = blockIdx.x * blockDim.x + threadIdx.x;
    if (i >= n) return;
    int b = i / SCAN_CHUNK;
    int v = excl[i] + (b > 0 ? lds[b - 1] : 0);
    excl[i] = v;                                        // excl becomes row_ptr
    if (i < nrows && (i & (BROWS - 1)) == 0) bcur[i >> BSHIFT] = v;
}

// ---- pass A: LDS-binned bucket scatter (coalesced staged writes) -----------
// staged record: (val fp32, meta = (lrow<<18)|col)
__global__ void bucket_scatter(const void* __restrict__ vals, const int* __restrict__ rows,
                               const int* __restrict__ cols, int* __restrict__ bcur,
                               float2* __restrict__ staged, int nnz, int nbuck,
                               const int* __restrict__ flagp) {
    __shared__ int hist[NBMAX];
    __shared__ int exb[NBMAX];
    __shared__ int gb[NBMAX];
    __shared__ int sc[NBMAX];
    __shared__ float2 st[TILE];
    __shared__ int bkt[TILE];
    int t = threadIdx.x;
    int bf = *flagp;

    for (int tile = blockIdx.x * TILE; tile < nnz; tile += gridDim.x * TILE) {
        int cnt = min(TILE, nnz - tile);
        for (int i = t; i < NBMAX; i += 256) hist[i] = 0;
        __syncthreads();

        int   myb[16], myo[16], mmeta[16];
        float mv[16];
#pragma unroll
        for (int k = 0; k < 16; ++k) {
            int i = tile + k * 256 + t;            // coalesced
            if (i < nnz && (k * 256 + t) < cnt) {
                int r = rows[i], c = cols[i];
                mv[k]    = ld_elem(vals, i, bf);
                myb[k]   = r >> BSHIFT;
                mmeta[k] = ((r & (BROWS - 1)) << 18) | c;
                myo[k]   = atomicAdd(&hist[myb[k]], 1);
            } else myb[k] = -1;
        }
        __syncthreads();

        // inclusive scan of hist over NBMAX=128 entries
        if (t < NBMAX) sc[t] = hist[t];
        __syncthreads();
        for (int off = 1; off < NBMAX; off <<= 1) {
            int v = 0;
            if (t < NBMAX) { v = sc[t]; if (t >= off) v += sc[t - off]; }
            __syncthreads();
            if (t < NBMAX) sc[t] = v;
            __syncthreads();
        }
        if (t < NBMAX) {
            exb[t] = sc[t] - hist[t];
            if (t < nbuck && hist[t] > 0) gb[t] = atomicAdd(&bcur[t], hist[t]);
        }
        __syncthreads();

#pragma unroll
        for (int k = 0; k < 16; ++k) {
            if (myb[k] >= 0) {
                int p = exb[myb[k]] + myo[k];
                st[p]  = make_float2(mv[k], __int_as_float(mmeta[k]));
                bkt[p] = myb[k];
            }
        }
        __syncthreads();

        // coalesced copy-out: consecutive p in same bucket -> consecutive dest
        for (int p = t; p < cnt; p += 256) {
            int b = bkt[p];
            staged[gb[b] + (p - exb[b])] = st[p];
        }
        __syncthreads();
    }
}

// ---- pass B: per-bucket exact CSR placement (LDS cursors, L2-local writes) --
__global__ void bucket_place(const int* __restrict__ row_ptr,
                             const float2* __restrict__ staged,
                             float2* __restrict__ edges, int nrows) {
    __shared__ int loffs[BROWS];
    int b = blockIdx.x;
    int rlo = b << BSHIFT;
    int rhi = min(rlo + BROWS, nrows);
    int nr  = rhi - rlo;
    int base = row_ptr[rlo];
    int end  = row_ptr[rhi];
    for (int i = threadIdx.x; i < nr; i += 256) loffs[i] = row_ptr[rlo + i] - base;
    __syncthreads();
    for (int p = base + threadIdx.x; p < end; p += 256) {
        float2 rec = staged[p];
        int meta = __float_as_int(rec.y);
        int lr = meta >> 18;
        int c  = meta & 0x3FFFF;
        int pos = atomicAdd(&loffs[lr], 1);
        edges[base + pos] = make_float2(rec.x, __int_as_float(c));
    }
}

// ---- 4-elem gather helpers (elem index = 4 consecutive dims) ----------------
__device__ __forceinline__ float4 ld4_x0(const void* uw, const void* iw,
                                         int n_user_elems, long long e, int bf) {
    const void* base = uw;
    if (e >= (long long)n_user_elems) { base = iw; e -= n_user_elems; }
    if (bf) {
        uint2 r = *reinterpret_cast<const uint2*>((const unsigned short*)base + e);
        return make_float4(__uint_as_float((r.x & 0xFFFFu) << 16),
                           __uint_as_float(r.x & 0xFFFF0000u),
                           __uint_as_float((r.y & 0xFFFFu) << 16),
                           __uint_as_float(r.y & 0xFFFF0000u));
    }
    return *reinterpret_cast<const float4*>((const float*)base + e);
}

__device__ __forceinline__ float4 ld4_f16(const __half* g, long long e) {
    uint2 r = *reinterpret_cast<const uint2*>(g + e);
    union { unsigned int u; __half2 h; } c0, c1;
    c0.u = r.x; c1.u = r.y;
    float2 f0 = __half22float2(c0.h), f1 = __half22float2(c1.h);
    return make_float4(f0.x, f0.y, f1.x, f1.y);
}

// ---- gather-only SpMM: 4 rows per wave, 16 lanes per row, lane = 4 dims ----
template <int GMODE, int OMODE>
__global__ void spmm_csr4(const int* __restrict__ row_ptr,
                          const float2* __restrict__ edges,
                          const void* __restrict__ uw, const void* __restrict__ iw,
                          int n_user_elems,
                          const __half* __restrict__ gin, void* __restrict__ gout,
                          int nrows, const int* __restrict__ flagp) {
    int tid  = blockIdx.x * blockDim.x + threadIdx.x;
    int wave = tid >> 6;
    int lane = threadIdx.x & 63;
    int g    = lane >> 4;          // row slot within wave (0..3)
    int l    = lane & 15;          // dim quad: covers dims [4l, 4l+3]
    int wid  = wave * 4 + g;
    if (wid >= nrows) return;
    int bf = *flagp;
    int beg = row_ptr[wid], end = row_ptr[wid + 1];
    float a0 = 0.f, a1 = 0.f, a2 = 0.f, a3 = 0.f;

#define GATHER(E, X) { \
        long long ce = (long long)__float_as_int((E).y) * EMB + l * 4; \
        if (GMODE == 0) X = ld4_x0(uw, iw, n_user_elems, ce, bf); \
        else            X = ld4_f16(gin, ce); }
#define ACC(E, X) { a0 += (E).x * (X).x; a1 += (E).x * (X).y; \
                    a2 += (E).x * (X).z; a3 += (E).x * (X).w; }

    int j = beg;
    for (; j + 4 <= end; j += 4) {
        float2 e0 = edges[j], e1 = edges[j + 1], e2 = edges[j + 2], e3 = edges[j + 3];
        float4 xa, xb, xc, xd;
        GATHER(e0, xa); GATHER(e1, xb); GATHER(e2, xc); GATHER(e3, xd);
        ACC(e0, xa); ACC(e1, xb); ACC(e2, xc); ACC(e3, xd);
    }
    if (j + 2 <= end) {
        float2 e0 = edges[j], e1 = edges[j + 1];
        float4 xa, xb;
        GATHER(e0, xa); GATHER(e1, xb);
        ACC(e0, xa); ACC(e1, xb);
        j += 2;
    }
    if (j < end) {
        float2 e0 = edges[j];
        float4 xa; GATHER(e0, xa);
        ACC(e0, xa);
    }
#undef GATHER
#undef ACC

    long long re = (long long)wid * EMB + l * 4;
    float4 x0v = ld4_x0(uw, iw, n_user_elems, re, bf);
    float o0 = x0v.x + a0, o1 = x0v.y + a1, o2 = x0v.z + a2, o3 = x0v.w + a3;

    if (OMODE == 1) {
        __half2 h01 = __floats2half2_rn(o0, o1);
        __half2 h23 = __floats2half2_rn(o2, o3);
        union { __half2 h; unsigned int u; } p0, p1;
        p0.h = h01; p1.h = h23;
        uint2 out; out.x = p0.u; out.y = p1.u;
        reinterpret_cast<uint2*>(gout)[re >> 2] = out;
    } else {
        o0 *= 0.25f; o1 *= 0.25f; o2 *= 0.25f; o3 *= 0.25f;
        if (bf) {
            __hip_bfloat16 b0 = (__hip_bfloat16)o0, b1 = (__hip_bfloat16)o1;
            __hip_bfloat16 b2 = (__hip_bfloat16)o2, b3 = (__hip_bfloat16)o3;
            unsigned short s0 = *reinterpret_cast<unsigned short*>(&b0);
            unsigned short s1 = *reinterpret_cast<unsigned short*>(&b1);
            unsigned short s2 = *reinterpret_cast<unsigned short*>(&b2);
            unsigned short s3 = *reinterpret_cast<unsigned short*>(&b3);
            uint2 out;
            out.x = (unsigned int)s0 | ((unsigned int)s1 << 16);
            out.y = (unsigned int)s2 | ((unsigned int)s3 << 16);
            reinterpret_cast<uint2*>(gout)[re >> 2] = out;
        } else {
            reinterpret_cast<float4*>(gout)[re >> 2] = make_float4(o0, o1, o2, o3);
        }
    }
}

extern "C" void kernel_launch(void* const* d_in, const int* in_sizes, int n_in,
                              void* d_out, int out_size, void* d_ws, size_t ws_size,
                              hipStream_t stream) {
    const void* uw   = d_in[0];
    const void* iw   = d_in[1];
    const void* vals = d_in[2];
    const int*  rows = (const int*)d_in[3];
    const int*  cols = (const int*)d_in[4];

    const int n_user = in_sizes[0];                // 6.4M elems
    const int total  = in_sizes[0] + in_sizes[1];  // 12.8M elems
    const int nnz    = in_sizes[2];                // 1M edges
    const int nrows  = total / EMB;                // 200K
    const int nbuck  = (nrows + BROWS - 1) >> BSHIFT;  // 98

    // ---- workspace layout (256B-aligned) ----
    char* p = (char*)d_ws;
    auto alloc = [&](size_t bytes) { char* q = p; p += (bytes + 255) & ~(size_t)255; return q; };
    int*    flag    = (int*)   alloc(sizeof(int));
    int*    row_ptr = (int*)   alloc((size_t)(nrows + 1) * sizeof(int));
    int*    counts  = (int*)   alloc((size_t)(nrows + 1) * sizeof(int));
    int*    bcur    = (int*)   alloc(NBMAX * sizeof(int));
    int*    bsums   = (int*)   alloc(1024 * sizeof(int));
    float2* staged  = (float2*)alloc((size_t)nnz * sizeof(float2));
    float2* edges   = (float2*)alloc((size_t)nnz * sizeof(float2));
    size_t used = (size_t)(p - (char*)d_ws);
    size_t avail = (ws_size > used) ? ws_size - used : 0;

    const size_t g_f16 = (size_t)total * sizeof(__half);  // 25.6 MB
    __half *g2, *g3;
    if (avail >= 2 * g_f16 + 512) { g2 = (__half*)alloc(g_f16); g3 = (__half*)alloc(g_f16); }
    else { g2 = (__half*)d_out; g3 = (__half*)alloc(g_f16); }  // d_out dead-staged, overwritten at end

    // ---- CSR build (every call; capture-safe) ----
    hipMemsetAsync(counts, 0, (size_t)(nrows + 1) * sizeof(int), stream);
    const int hb = (nnz / 4 + 255) / 256;
    hist_rows<<<hb, 256, 0, stream>>>(rows, counts, nnz, (const unsigned short*)vals, flag);
    const int n_scan = nrows + 1;
    const int nb = (n_scan + SCAN_CHUNK - 1) / SCAN_CHUNK;   // 196 <= 256
    scan_blocks<<<nb, 256, 0, stream>>>(counts, row_ptr, bsums, n_scan);
    scan_fixup<<<(n_scan + 255) / 256, 256, 0, stream>>>(row_ptr, bsums, bcur, n_scan, nrows, nb);

    const int ntiles = (nnz + TILE - 1) / TILE;   // 245
    bucket_scatter<<<ntiles, 256, 0, stream>>>(vals, rows, cols, bcur, staged, nnz, nbuck, flag);
    bucket_place<<<nbuck, 256, 0, stream>>>(row_ptr, staged, edges, nrows);

    // ---- 3 gather-only SpMM layers (Horner), fp16 inter-layer staging ----
    const int nwaves = (nrows + 3) / 4;
    const int rb = (nwaves * 64 + 255) / 256;
    spmm_csr4<0, 1><<<rb, 256, 0, stream>>>(row_ptr, edges, uw, iw, n_user,
                                            nullptr, g2, nrows, flag);
    spmm_csr4<1, 1><<<rb, 256, 0, stream>>>(row_ptr, edges, uw, iw, n_user,
                                            g2, g3, nrows, flag);
    spmm_csr4<1, 3><<<rb, 256, 0, stream>>>(row_ptr, edges, uw, iw, n_user,
                                            g3, d_out, nrows, flag);
}